// Round 3
// baseline (327.799 us; speedup 1.0000x reference)
//
#include <hip/hip_runtime.h>

#define NEMB 512
#define DIM 64
#define NB 32
#define HW 4096                 // 64*64 spatial per batch
#define NTOK (NB * HW)          // 131072 tokens
#define TPB 256
#define BLOCKS (NTOK / TPB)     // 512
#define BLK_PER_B (HW / TPB)    // 16

// Pre-kernel: sumc[k] = sum_d cb[k][d]^2 — rounded squares, sequential adds
// (identical rounding to the previous passing version's sumc pass).
__global__ void vq_sumc(const float* __restrict__ cb, float* __restrict__ sumc)
{
    int k = blockIdx.x * 256 + threadIdx.x;
    if (k < NEMB) {
#pragma clang fp contract(off)
        float s = 0.f;
#pragma unroll
        for (int d = 0; d < DIM; ++d) {
            float v = cb[k * DIM + d];
            float p = v * v;
            s = s + p;
        }
        sumc[k] = s;
    }
}

// One token per thread. Codebook values are WAVE-UNIFORM -> scalar loads
// (s_load) feeding v_fma_f32 with an SGPR operand. No LDS staging at all.
// Per-chain FMA order over d is sequential (bit-exact match vs XLA confirmed
// by round-2 absmax=0.0); strict-< ascending-k argmin == jnp.argmin tie-break.
__global__ __launch_bounds__(TPB, 2)
void vq_main(const float* __restrict__ z_e, const float* __restrict__ cb,
             const float* __restrict__ sumc,
             float* __restrict__ out, float* __restrict__ loss_part,
             float* __restrict__ inds_out)
{
    __shared__ float red_s[TPB];

    const int tid = threadIdx.x;
    const int gid = blockIdx.x;
    const int b   = gid / BLK_PER_B;
    const int hw  = (gid % BLK_PER_B) * TPB + tid;

    const float* zb = z_e + (size_t)b * DIM * HW;

    // Token into registers; sumz = sum of rounded squares, sequential adds.
    float z[DIM];
    float sumz = 0.f;
    {
#pragma clang fp contract(off)
#pragma unroll
        for (int d = 0; d < DIM; ++d) {
            float v = zb[(size_t)d * HW + hw];   // coalesced across lanes
            z[d] = v;
            float p = v * v;
            sumz = sumz + p;
        }
    }

    const float4* cb4 = (const float4*)cb;   // uniform (lane-invariant) reads
    float best  = 3.402823466e38f;
    int   bestk = 0;

    for (int k = 0; k < NEMB; k += 2) {
        float acc0 = 0.f, acc1 = 0.f;
#pragma unroll
        for (int g = 0; g < DIM / 4; ++g) {
            float4 c0 = cb4[(size_t)k * (DIM / 4) + g];
            float4 c1 = cb4[(size_t)(k + 1) * (DIM / 4) + g];
            // two independent chains (ILP); each chain d-sequential
            acc0 = fmaf(z[4 * g + 0], c0.x, acc0);
            acc0 = fmaf(z[4 * g + 1], c0.y, acc0);
            acc0 = fmaf(z[4 * g + 2], c0.z, acc0);
            acc0 = fmaf(z[4 * g + 3], c0.w, acc0);
            acc1 = fmaf(z[4 * g + 0], c1.x, acc1);
            acc1 = fmaf(z[4 * g + 1], c1.y, acc1);
            acc1 = fmaf(z[4 * g + 2], c1.z, acc1);
            acc1 = fmaf(z[4 * g + 3], c1.w, acc1);
        }
        // same source expression as the bit-exact round-2 version
        float d2a = (sumz - 2.0f * acc0) + sumc[k];
        float d2b = (sumz - 2.0f * acc1) + sumc[k + 1];
        if (d2a < best) { best = d2a; bestk = k; }
        if (d2b < best) { best = d2b; bestk = k + 1; }
    }

    // ---- epilogue (identical to passing version) ----
    inds_out[(size_t)gid * TPB + tid] = (float)bestk;

    const float4* q4 = (const float4*)(cb + (size_t)bestk * DIM);
    float*        ob = out + (size_t)b * DIM * HW;
    float lsum = 0.f;
    {
#pragma clang fp contract(off)
#pragma unroll
        for (int g = 0; g < DIM / 4; ++g) {
            float4 q = q4[g];
            float qv[4] = {q.x, q.y, q.z, q.w};
#pragma unroll
            for (int j = 0; j < 4; ++j) {
                int d = g * 4 + j;
                float t1 = qv[j] - z[d];              // fl(z_q - z)
                ob[(size_t)d * HW + hw] = z[d] + t1;  // fl(z + fl(z_q - z))
                float p = t1 * t1;
                lsum = lsum + p;
            }
        }
    }

    __syncthreads();
    red_s[tid] = lsum;
    __syncthreads();
#pragma unroll
    for (int s = TPB / 2; s > 0; s >>= 1) {
        if (tid < s) red_s[tid] = red_s[tid] + red_s[tid + s];
        __syncthreads();
    }
    if (tid == 0) loss_part[gid] = red_s[0];
}

// deterministic final reduce: 16 partials per batch, fixed order
__global__ void vq_loss_final(const float* __restrict__ part,
                              float* __restrict__ loss_out)
{
    int b = threadIdx.x;
    if (b < NB) {
        float s = 0.f;
        for (int i = 0; i < BLK_PER_B; ++i)
            s = s + part[b * BLK_PER_B + i];
        float m = s * (1.0f / (HW * DIM));   // exact /2^18
        loss_out[b] = m + 0.25f * m;
    }
}

extern "C" void kernel_launch(void* const* d_in, const int* in_sizes, int n_in,
                              void* d_out, int out_size, void* d_ws, size_t ws_size,
                              hipStream_t stream)
{
    const float* z_e = (const float*)d_in[0];
    const float* cb  = (const float*)d_in[1];

    float* out  = (float*)d_out;
    float* loss = out + (size_t)NB * DIM * HW;  // offset 8388608
    float* inds = loss + NB;                    // offset 8388640

    float* part  = (float*)d_ws;                // [512] loss partials
    float* sumcg = part + BLOCKS;               // [512] codebook row norms

    vq_sumc<<<2, TPB, 0, stream>>>(cb, sumcg);
    vq_main<<<BLOCKS, TPB, 0, stream>>>(z_e, cb, sumcg, out, part, inds);
    vq_loss_final<<<1, 64, 0, stream>>>(part, loss);
}

// Round 6
// 151.315 us; speedup vs baseline: 2.1663x; 2.1663x over previous
//
#include <hip/hip_runtime.h>

#define NEMB 512
#define DIM 64
#define NB 32
#define HW 4096                   // 64*64 spatial per batch
#define NTOK (NB * HW)            // 131072 tokens
#define TPB 256
#define TPT 2                     // tokens per thread
#define TOK_PER_BLK (TPB * TPT)   // 512
#define BLOCKS (NTOK / TOK_PER_BLK)   // 256  (== #CUs, 1 block/CU)
#define CHUNKS_PER_B (HW / TOK_PER_BLK) // 8 blocks per batch

// sumc[k] = sum_d cb[k][d]^2 — rounded squares, sequential adds (bit-exact,
// verified R2/R3).
__global__ void vq_sumc(const float* __restrict__ cb, float* __restrict__ sumc)
{
    int k = blockIdx.x * 256 + threadIdx.x;
    if (k < NEMB) {
#pragma clang fp contract(off)
        float s = 0.f;
#pragma unroll
        for (int d = 0; d < DIM; ++d) {
            float v = cb[k * DIM + d];
            float p = v * v;
            s = s + p;
        }
        sumc[k] = s;
    }
}

// 2 tokens/thread; FULL codebook (128 KB) staged in LDS once; each LDS
// broadcast read feeds 2 tokens (halved DS traffic per FMA vs R2).
// All rounding-sensitive orders identical to the bit-exact R2 kernel.
__global__ __launch_bounds__(TPB, 1)
void vq_main(const float* __restrict__ z_e, const float* __restrict__ cb,
             const float* __restrict__ sumc,
             float* __restrict__ out, float* __restrict__ loss_part,
             float* __restrict__ inds_out)
{
    __shared__ float cb_s[NEMB][DIM];   // 128 KB
    __shared__ float sumc_s[NEMB];      // 2 KB
    __shared__ float red_s[TPB];        // 1 KB

    const int tid  = threadIdx.x;
    const int gid  = blockIdx.x;
    const int b    = gid / CHUNKS_PER_B;
    const int base = (gid % CHUNKS_PER_B) * TOK_PER_BLK;
    const int hw0  = base + tid;          // token A
    const int hw1  = base + TPB + tid;    // token B

    // ---- stage codebook + sumc into LDS (coalesced float4) ----
    {
        const float4* s4 = (const float4*)cb;
        float4*       d4 = (float4*)&cb_s[0][0];
#pragma unroll
        for (int i = 0; i < (NEMB * DIM / 4) / TPB; ++i)   // 128 iters
            d4[i * TPB + tid] = s4[i * TPB + tid];
        sumc_s[tid]       = sumc[tid];
        sumc_s[tid + TPB] = sumc[tid + TPB];
    }

    const float* zb = z_e + (size_t)b * DIM * HW;

    // ---- tokens into registers; sumz rounded-squares, d-ascending ----
    float z0[DIM], z1[DIM];
    float sumz0 = 0.f, sumz1 = 0.f;
    {
#pragma clang fp contract(off)
#pragma unroll
        for (int d = 0; d < DIM; ++d) {
            float v = zb[(size_t)d * HW + hw0];
            z0[d] = v;
            float p = v * v;
            sumz0 = sumz0 + p;
        }
#pragma unroll
        for (int d = 0; d < DIM; ++d) {
            float v = zb[(size_t)d * HW + hw1];
            z1[d] = v;
            float p = v * v;
            sumz1 = sumz1 + p;
        }
    }

    __syncthreads();

    float best0 = 3.402823466e38f, best1 = 3.402823466e38f;
    int   bk0 = 0, bk1 = 0;

    for (int k = 0; k < NEMB; k += 2) {
        const float4* c0 = (const float4*)&cb_s[k][0];
        const float4* c1 = (const float4*)&cb_s[k + 1][0];
        float a00 = 0.f, a01 = 0.f, a10 = 0.f, a11 = 0.f; // tok x code chains
#pragma unroll
        for (int g = 0; g < DIM / 4; ++g) {
            float4 u = c0[g];
            float4 v = c1[g];
            // each chain strictly d-ascending (bit-exact order, as R2)
            a00 = fmaf(z0[4 * g + 0], u.x, a00);
            a00 = fmaf(z0[4 * g + 1], u.y, a00);
            a00 = fmaf(z0[4 * g + 2], u.z, a00);
            a00 = fmaf(z0[4 * g + 3], u.w, a00);
            a01 = fmaf(z0[4 * g + 0], v.x, a01);
            a01 = fmaf(z0[4 * g + 1], v.y, a01);
            a01 = fmaf(z0[4 * g + 2], v.z, a01);
            a01 = fmaf(z0[4 * g + 3], v.w, a01);
            a10 = fmaf(z1[4 * g + 0], u.x, a10);
            a10 = fmaf(z1[4 * g + 1], u.y, a10);
            a10 = fmaf(z1[4 * g + 2], u.z, a10);
            a10 = fmaf(z1[4 * g + 3], u.w, a10);
            a11 = fmaf(z1[4 * g + 0], v.x, a11);
            a11 = fmaf(z1[4 * g + 1], v.y, a11);
            a11 = fmaf(z1[4 * g + 2], v.z, a11);
            a11 = fmaf(z1[4 * g + 3], v.w, a11);
        }
        // same source expression / pragma context as the bit-exact R2 loop
        float d2a0 = (sumz0 - 2.0f * a00) + sumc_s[k];
        float d2b0 = (sumz0 - 2.0f * a01) + sumc_s[k + 1];
        float d2a1 = (sumz1 - 2.0f * a10) + sumc_s[k];
        float d2b1 = (sumz1 - 2.0f * a11) + sumc_s[k + 1];
        if (d2a0 < best0) { best0 = d2a0; bk0 = k; }
        if (d2b0 < best0) { best0 = d2b0; bk0 = k + 1; }
        if (d2a1 < best1) { best1 = d2a1; bk1 = k; }
        if (d2b1 < best1) { best1 = d2b1; bk1 = k + 1; }
    }

    // ---- epilogue (textually R2 per token; pragma FIRST in block) ----
    inds_out[(size_t)gid * TOK_PER_BLK + tid]       = (float)bk0;
    inds_out[(size_t)gid * TOK_PER_BLK + TPB + tid] = (float)bk1;

    float* ob = out + (size_t)b * DIM * HW;
    float lsum0 = 0.f, lsum1 = 0.f;
    const float4* q4a = (const float4*)(cb + (size_t)bk0 * DIM);
    const float4* q4b = (const float4*)(cb + (size_t)bk1 * DIM);
    {
#pragma clang fp contract(off)
#pragma unroll
        for (int g = 0; g < DIM / 4; ++g) {
            float4 q = q4a[g];
            float qv[4] = {q.x, q.y, q.z, q.w};
#pragma unroll
            for (int j = 0; j < 4; ++j) {
                int d = g * 4 + j;
                float t1 = qv[j] - z0[d];              // fl(z_q - z)
                ob[(size_t)d * HW + hw0] = z0[d] + t1; // fl(z + fl(z_q - z))
                float p = t1 * t1;
                lsum0 = lsum0 + p;
            }
        }
    }
    {
#pragma clang fp contract(off)
#pragma unroll
        for (int g = 0; g < DIM / 4; ++g) {
            float4 q = q4b[g];
            float qv[4] = {q.x, q.y, q.z, q.w};
#pragma unroll
            for (int j = 0; j < 4; ++j) {
                int d = g * 4 + j;
                float t1 = qv[j] - z1[d];
                ob[(size_t)d * HW + hw1] = z1[d] + t1;
                float p = t1 * t1;
                lsum1 = lsum1 + p;
            }
        }
    }

    // ---- two 256-leaf trees -> 2 partials/block == R2's exact association
    // (16 partials per batch, same leaf order, same tree shape) ----
    __syncthreads();
    red_s[tid] = lsum0;
    __syncthreads();
#pragma unroll
    for (int s = TPB / 2; s > 0; s >>= 1) {
        if (tid < s) red_s[tid] = red_s[tid] + red_s[tid + s];
        __syncthreads();
    }
    if (tid == 0) loss_part[2 * gid] = red_s[0];
    __syncthreads();
    red_s[tid] = lsum1;
    __syncthreads();
#pragma unroll
    for (int s = TPB / 2; s > 0; s >>= 1) {
        if (tid < s) red_s[tid] = red_s[tid] + red_s[tid + s];
        __syncthreads();
    }
    if (tid == 0) loss_part[2 * gid + 1] = red_s[0];
}

// deterministic final reduce: 16 partials per batch, fixed order (== R2)
__global__ void vq_loss_final(const float* __restrict__ part,
                              float* __restrict__ loss_out)
{
    int b = threadIdx.x;
    if (b < NB) {
        float s = 0.f;
        for (int i = 0; i < 16; ++i)
            s = s + part[b * 16 + i];
        float m = s * (1.0f / (HW * DIM));   // exact /2^18
        loss_out[b] = m + 0.25f * m;
    }
}

extern "C" void kernel_launch(void* const* d_in, const int* in_sizes, int n_in,
                              void* d_out, int out_size, void* d_ws, size_t ws_size,
                              hipStream_t stream)
{
    const float* z_e = (const float*)d_in[0];
    const float* cb  = (const float*)d_in[1];

    float* out  = (float*)d_out;
    float* loss = out + (size_t)NB * DIM * HW;  // offset 8388608
    float* inds = loss + NB;                    // offset 8388640

    float* part  = (float*)d_ws;                // [512] loss partials
    float* sumcg = part + 512;                  // [512] codebook row norms

    vq_sumc<<<2, TPB, 0, stream>>>(cb, sumcg);
    vq_main<<<BLOCKS, TPB, 0, stream>>>(z_e, cb, sumcg, out, part, inds);
    vq_loss_final<<<1, 64, 0, stream>>>(part, loss);
}